// Round 4
// baseline (251.249 us; speedup 1.0000x reference)
//
#include <hip/hip_runtime.h>
#include <math.h>

#define BLOCK 256
#define XW 13
#define PW 30

// Per-patient derivative. X[13] states, P[30] params (column order per reference).
__device__ __forceinline__ void dxdt(const float* X, const float* P,
                                     float ai, float cho, float lq, float lf,
                                     float* dx)
{
    const float BW = P[0],  KMAX = P[1],  B   = P[2],  D   = P[3],  KMIN = P[4];
    const float KABS = P[5], F   = P[6],  KP1 = P[7],  KP2 = P[8],  KP3  = P[9];
    const float FSNC = P[10], KE1 = P[11], KE2 = P[12], K1 = P[13], K2   = P[14];
    const float VM0 = P[15], VMX = P[16], KM0 = P[17], M1 = P[18], M2   = P[19];
    const float M4  = P[20], KA1 = P[21], KA2 = P[22], VI = P[23], P2U  = P[24];
    const float IB  = P[25], KI  = P[26], M30 = P[27], KD = P[28], KSC  = P[29];

    const float f_insulin = ai * 6000.0f / BW;
    const float qsto = X[0] + X[1];
    const float Dbar = lq + lf;

    dx[0] = -KMAX * X[0] + cho * 1000.0f;

    const float inv_dbar = 1.0f / (Dbar + 1e-7f);
    const float aa = 2.5f / (1.0f - B) * inv_dbar;
    const float cc = 2.5f / D * inv_dbar;
    const float kgut_true = KMIN + (KMAX - KMIN) * 0.5f *
        (tanhf(aa * (qsto - B * Dbar)) - tanhf(cc * (qsto - D * Dbar)) + 2.0f);
    const float kgut = (Dbar > 0.0f) ? kgut_true : KMAX;

    dx[1] = KMAX * X[0] - X[1] * kgut;
    dx[2] = kgut * X[1] - KABS * X[2];

    const float Rat  = F * KABS * X[2] / BW;
    const float EGPt = KP1 - KP2 * X[3] - KP3 * X[8];
    const float Et   = (X[3] > KE2) ? KE1 * (X[3] - KE2) : 0.0f;
    const float d3 = fmaxf(EGPt, 0.0f) + Rat - FSNC - Et - K1 * X[3] + K2 * X[4];
    dx[3] = (X[3] >= 0.0f) ? d3 : 0.0f;

    const float Vmt  = VM0 + VMX * X[6];
    const float Uidt = Vmt * X[4] / (KM0 + X[4]);
    const float d4 = -Uidt + K1 * X[3] - K2 * X[4];
    dx[4] = (X[4] >= 0.0f) ? d4 : 0.0f;

    const float d5 = -(M2 + M4) * X[5] + M1 * X[9] + KA1 * X[10] + KA2 * X[11];
    const float It = X[5] / VI;
    dx[5] = (X[5] >= 0.0f) ? d5 : 0.0f;

    dx[6] = -P2U * X[6] + P2U * (It - IB);
    dx[7] = -KI * (X[7] - It);
    dx[8] = -KI * (X[8] - X[7]);

    const float d9 = -(M1 + M30) * X[9] + M2 * X[5];
    dx[9] = (X[9] >= 0.0f) ? d9 : 0.0f;

    const float d10 = f_insulin - (KA1 + KD) * X[10];
    dx[10] = (X[10] >= 0.0f) ? d10 : 0.0f;

    const float d11 = KD * X[10] - KA2 * X[11];
    dx[11] = (X[11] >= 0.0f) ? d11 : 0.0f;

    const float d12 = -KSC * X[12] + KSC * X[3];
    dx[12] = (X[12] >= 0.0f) ? d12 : 0.0f;
}

// R4 experiment: ZERO LDS, ZERO barriers, pure per-thread direct loads.
// R1 vs R3 showed staging mechanics don't matter (92 vs 87 us) — the common
// limiter was the 44KB-LDS occupancy cap (3 blocks/CU) + barrier convoy.
// Per-thread rows are contiguous (13 / 30 dwords); a wave's 13 x-loads all
// land in the same ~27 cache lines -> 100% line utilization, no over-fetch.
// ~43 independent loads in flight per thread, no waits until first use.
__global__ __launch_bounds__(BLOCK) void t1d_kernel(
    const float* __restrict__ x,
    const float* __restrict__ params,
    const float* __restrict__ action_ins,
    const float* __restrict__ action_CHO,
    const float* __restrict__ last_Qsto,
    const float* __restrict__ last_foodtaken,
    float* __restrict__ out, int n)
{
    const size_t i = (size_t)blockIdx.x * BLOCK + threadIdx.x;
    if (i >= (size_t)n) return;

    const float* __restrict__ xr = x + i * XW;
    const float* __restrict__ pr = params + i * PW;

    float X[XW], P[PW], dx[XW];
    #pragma unroll
    for (int j = 0; j < XW; ++j) X[j] = xr[j];
    #pragma unroll
    for (int j = 0; j < PW; ++j) P[j] = pr[j];

    const float ai  = action_ins[i];
    const float cho = action_CHO[i];
    const float lq  = last_Qsto[i];
    const float lf  = last_foodtaken[i];

    dxdt(X, P, ai, cho, lq, lf, dx);

    float* __restrict__ o = out + i * XW;
    #pragma unroll
    for (int j = 0; j < XW; ++j) o[j] = dx[j];
}

extern "C" void kernel_launch(void* const* d_in, const int* in_sizes, int n_in,
                              void* d_out, int out_size, void* d_ws, size_t ws_size,
                              hipStream_t stream) {
    const float* x      = (const float*)d_in[0];
    const float* params = (const float*)d_in[1];
    const float* ai     = (const float*)d_in[2];
    const float* cho    = (const float*)d_in[3];
    const float* lq     = (const float*)d_in[4];
    const float* lf     = (const float*)d_in[5];
    float* out = (float*)d_out;

    const int n = in_sizes[0] / XW;          // number of patients
    const int grid = (n + BLOCK - 1) / BLOCK;
    t1d_kernel<<<grid, BLOCK, 0, stream>>>(x, params, ai, cho, lq, lf, out, n);
}

// Round 5
// 247.625 us; speedup vs baseline: 1.0146x; 1.0146x over previous
//
#include <hip/hip_runtime.h>
#include <math.h>

#define WAVE 64
#define XW 13
#define PW 30

// Per-patient derivative. X[13] states, P[30] params (column order per reference).
__device__ __forceinline__ void dxdt(const float* X, const float* P,
                                     float ai, float cho, float lq, float lf,
                                     float* dx)
{
    const float BW = P[0],  KMAX = P[1],  B   = P[2],  D   = P[3],  KMIN = P[4];
    const float KABS = P[5], F   = P[6],  KP1 = P[7],  KP2 = P[8],  KP3  = P[9];
    const float FSNC = P[10], KE1 = P[11], KE2 = P[12], K1 = P[13], K2   = P[14];
    const float VM0 = P[15], VMX = P[16], KM0 = P[17], M1 = P[18], M2   = P[19];
    const float M4  = P[20], KA1 = P[21], KA2 = P[22], VI = P[23], P2U  = P[24];
    const float IB  = P[25], KI  = P[26], M30 = P[27], KD = P[28], KSC  = P[29];

    const float f_insulin = ai * 6000.0f / BW;
    const float qsto = X[0] + X[1];
    const float Dbar = lq + lf;

    dx[0] = -KMAX * X[0] + cho * 1000.0f;

    const float inv_dbar = 1.0f / (Dbar + 1e-7f);
    const float aa = 2.5f / (1.0f - B) * inv_dbar;
    const float cc = 2.5f / D * inv_dbar;
    const float kgut_true = KMIN + (KMAX - KMIN) * 0.5f *
        (tanhf(aa * (qsto - B * Dbar)) - tanhf(cc * (qsto - D * Dbar)) + 2.0f);
    const float kgut = (Dbar > 0.0f) ? kgut_true : KMAX;

    dx[1] = KMAX * X[0] - X[1] * kgut;
    dx[2] = kgut * X[1] - KABS * X[2];

    const float Rat  = F * KABS * X[2] / BW;
    const float EGPt = KP1 - KP2 * X[3] - KP3 * X[8];
    const float Et   = (X[3] > KE2) ? KE1 * (X[3] - KE2) : 0.0f;
    const float d3 = fmaxf(EGPt, 0.0f) + Rat - FSNC - Et - K1 * X[3] + K2 * X[4];
    dx[3] = (X[3] >= 0.0f) ? d3 : 0.0f;

    const float Vmt  = VM0 + VMX * X[6];
    const float Uidt = Vmt * X[4] / (KM0 + X[4]);
    const float d4 = -Uidt + K1 * X[3] - K2 * X[4];
    dx[4] = (X[4] >= 0.0f) ? d4 : 0.0f;

    const float d5 = -(M2 + M4) * X[5] + M1 * X[9] + KA1 * X[10] + KA2 * X[11];
    const float It = X[5] / VI;
    dx[5] = (X[5] >= 0.0f) ? d5 : 0.0f;

    dx[6] = -P2U * X[6] + P2U * (It - IB);
    dx[7] = -KI * (X[7] - It);
    dx[8] = -KI * (X[8] - X[7]);

    const float d9 = -(M1 + M30) * X[9] + M2 * X[5];
    dx[9] = (X[9] >= 0.0f) ? d9 : 0.0f;

    const float d10 = f_insulin - (KA1 + KD) * X[10];
    dx[10] = (X[10] >= 0.0f) ? d10 : 0.0f;

    const float d11 = KD * X[10] - KA2 * X[11];
    dx[11] = (X[11] >= 0.0f) ? d11 : 0.0f;

    const float d12 = -KSC * X[12] + KSC * X[3];
    dx[12] = (X[12] >= 0.0f) ? d12 : 0.0f;
}

// R5: one wave per block, wave-private LDS, NO barriers, NO DMA builtin.
// All global traffic is coalesced float4 (like the 6.3 TB/s copy ubench);
// 14 fully-independent waves/CU each keep ~12 KB in flight.
// launch_bounds(64,4): 128-VGPR budget so the 12 staging float4s (48 VGPRs)
// stay in registers (R2 spill sentinel: WRITE_SIZE must stay 53248 KiB).
__global__ __launch_bounds__(WAVE, 4) void t1d_kernel(
    const float* __restrict__ x,
    const float* __restrict__ params,
    const float* __restrict__ action_ins,
    const float* __restrict__ action_CHO,
    const float* __restrict__ last_Qsto,
    const float* __restrict__ last_foodtaken,
    float* __restrict__ out, int n)
{
    __shared__ float xb[WAVE * XW];   // 3328 B  (208 float4) — doubles as out staging
    __shared__ float pb[WAVE * PW];   // 7680 B  (480 float4)

    const int l = threadIdx.x;        // lane 0..63
    const size_t base = (size_t)blockIdx.x * WAVE;

    if (base + WAVE <= (size_t)n) {
        const float4* xg = (const float4*)(x + base * XW);       // 3328B-aligned
        const float4* pg = (const float4*)(params + base * PW);  // 7680B-aligned
        float4* xl4 = (float4*)xb;
        float4* pl4 = (float4*)pb;

        // ---- issue ALL 16 independent global loads (no consumer until writes) ----
        float4 a0 = xg[l];
        float4 a1 = xg[l + 64];
        float4 a2 = xg[l + 128];
        float4 a3; if (l < 16) a3 = xg[192 + l];        // 208 = 3*64 + 16

        float4 b0 = pg[l];
        float4 b1 = pg[l + 64];
        float4 b2 = pg[l + 128];
        float4 b3 = pg[l + 192];
        float4 b4 = pg[l + 256];
        float4 b5 = pg[l + 320];
        float4 b6 = pg[l + 384];
        float4 b7; if (l < 32) b7 = pg[448 + l];        // 480 = 7*64 + 32

        const float ai  = action_ins[base + l];
        const float cho = action_CHO[base + l];
        const float lq  = last_Qsto[base + l];
        const float lf  = last_foodtaken[base + l];

        // ---- spill to wave-private LDS (fine-grained vmcnt waits) ----
        xl4[l]       = a0;
        xl4[l + 64]  = a1;
        xl4[l + 128] = a2;
        if (l < 16) xl4[192 + l] = a3;
        pl4[l]       = b0;
        pl4[l + 64]  = b1;
        pl4[l + 128] = b2;
        pl4[l + 192] = b3;
        pl4[l + 256] = b4;
        pl4[l + 320] = b5;
        pl4[l + 384] = b6;
        if (l < 32) pl4[448 + l] = b7;

        // same-wave LDS RAW: compiler inserts lgkmcnt, no barrier needed
        float X[XW], P[PW], dx[XW];
        #pragma unroll
        for (int j = 0; j < XW; ++j) X[j] = xb[l * XW + j];   // stride 13: <=2-way, free
        #pragma unroll
        for (int j = 0; j < PW; ++j) P[j] = pb[l * PW + j];   // stride 30: 4-way, cheap

        dxdt(X, P, ai, cho, lq, lf, dx);

        // out through LDS for coalesced float4 stores
        #pragma unroll
        for (int j = 0; j < XW; ++j) xb[l * XW + j] = dx[j];

        float4 o0 = xl4[l];
        float4 o1 = xl4[l + 64];
        float4 o2 = xl4[l + 128];
        float4 o3; if (l < 16) o3 = xl4[192 + l];
        float4* og = (float4*)(out + base * XW);
        og[l]       = o0;
        og[l + 64]  = o1;
        og[l + 128] = o2;
        if (l < 16) og[192 + l] = o3;
    } else {
        // tail block (not hit for N=2^20): scalar path
        const size_t i = base + l;
        if (i < (size_t)n) {
            float X[XW], P[PW], dx[XW];
            #pragma unroll
            for (int j = 0; j < XW; ++j) X[j] = x[i * XW + j];
            #pragma unroll
            for (int j = 0; j < PW; ++j) P[j] = params[i * PW + j];
            dxdt(X, P, action_ins[i], action_CHO[i], last_Qsto[i],
                 last_foodtaken[i], dx);
            #pragma unroll
            for (int j = 0; j < XW; ++j) out[i * XW + j] = dx[j];
        }
    }
}

extern "C" void kernel_launch(void* const* d_in, const int* in_sizes, int n_in,
                              void* d_out, int out_size, void* d_ws, size_t ws_size,
                              hipStream_t stream) {
    const float* x      = (const float*)d_in[0];
    const float* params = (const float*)d_in[1];
    const float* ai     = (const float*)d_in[2];
    const float* cho    = (const float*)d_in[3];
    const float* lq     = (const float*)d_in[4];
    const float* lf     = (const float*)d_in[5];
    float* out = (float*)d_out;

    const int n = in_sizes[0] / XW;          // number of patients
    const int grid = (n + WAVE - 1) / WAVE;
    t1d_kernel<<<grid, WAVE, 0, stream>>>(x, params, ai, cho, lq, lf, out, n);
}